// Round 11
// baseline (231.372 us; speedup 1.0000x reference)
//
#include <hip/hip_runtime.h>

// ArtNetwork: y = sigmoid(Wout @ tanh(W8 @ ... tanh(W1 @ tanh(Win@x+b)) ...))
// Design (R11) = R10 + two calibrated tweaks:
//  (1) PER-VALUE v_rcp_f32 (drop product trees). R6->R10 A/B showed rcp ~4 cyc
//      (removing 9 rcps moved busy only ~32 cyc), so tree sharing (21 muls) was
//      a net loss vs 8 rcps (32 cyc). Shorter dep chains, fewer live regs.
//  (2) __launch_bounds__(256,8): VGPR=40 fits the 64-reg cap, residency
//      24->32 waves/CU to close the ~13% wall-vs-busy gap (R10 occupancy 52%).
//  Core structure (validated R6): propagate v = 1/(1+exp2(y)); tanh = 1-2v
//  folded into next layer via A=-2*K2*W and C-operand = K2*rowsum(W). All
//  layers (input/hidden/output) as v_mfma_f32_16x16x16_f16; C/D layout == B
//  layout so MFMA out -> v8 -> next B frag. No LDS, no shuffles in loop.
//  Straight-line scalar f32 activation code (R8 lesson: no arrays).
//  Calibrated cost model: main=2cyc, exp2=16cyc, rcp=4cyc per wave64 op, additive.

typedef float  f32x4 __attribute__((ext_vector_type(4)));
typedef __fp16 f16x4 __attribute__((ext_vector_type(4)));
typedef __fp16 f16x2 __attribute__((ext_vector_type(2)));

#define K2   2.8853900817779268f    // 2*log2(e): exp2(K2*z) = e^{2z}
#define KOUT (-1.4426950408889634f) // -log2(e):  exp2(KOUT*z) = e^{-z}

// v_i = 1/(1+exp2(y_i)) for 8 values (two MFMA accs), per-value rcp.
__device__ __forceinline__ void v8pv(f32x4 ya, f32x4 yb, f16x4* oa, f16x4* ob) {
    float v0 = __builtin_amdgcn_rcpf(__builtin_amdgcn_exp2f(ya[0]) + 1.0f);
    float v1 = __builtin_amdgcn_rcpf(__builtin_amdgcn_exp2f(ya[1]) + 1.0f);
    float v2 = __builtin_amdgcn_rcpf(__builtin_amdgcn_exp2f(ya[2]) + 1.0f);
    float v3 = __builtin_amdgcn_rcpf(__builtin_amdgcn_exp2f(ya[3]) + 1.0f);
    float v4 = __builtin_amdgcn_rcpf(__builtin_amdgcn_exp2f(yb[0]) + 1.0f);
    float v5 = __builtin_amdgcn_rcpf(__builtin_amdgcn_exp2f(yb[1]) + 1.0f);
    float v6 = __builtin_amdgcn_rcpf(__builtin_amdgcn_exp2f(yb[2]) + 1.0f);
    float v7 = __builtin_amdgcn_rcpf(__builtin_amdgcn_exp2f(yb[3]) + 1.0f);
    f16x2 a01 = __builtin_amdgcn_cvt_pkrtz(v0, v1);
    f16x2 a23 = __builtin_amdgcn_cvt_pkrtz(v2, v3);
    f16x2 b01 = __builtin_amdgcn_cvt_pkrtz(v4, v5);
    f16x2 b23 = __builtin_amdgcn_cvt_pkrtz(v6, v7);
    *oa = __builtin_shufflevector(a01, a23, 0, 1, 2, 3);
    *ob = __builtin_shufflevector(b01, b23, 0, 1, 2, 3);
}

__global__ __launch_bounds__(256, 8)
void artnet_kernel(const float2* __restrict__ x,     // [N][2]
                   const float2* __restrict__ Win,   // [16][2]
                   const float*  __restrict__ bin,   // [16]
                   const float4* __restrict__ Wh,    // [8][16][16]
                   const float4* __restrict__ Wout,  // [3][16]
                   float* __restrict__ out,          // [N][3]
                   int nPairs, int nWaves)
{
    const int tid  = blockIdx.x * 256 + threadIdx.x;
    const int gw   = tid >> 6;            // global wave id
    const int lane = threadIdx.x & 63;
    const int row  = lane & 15;           // m / point-col index
    const int quad = lane >> 4;           // 0..3

    // ---- Hidden layers: A = -2*K2*W (f16), C = K2*rowsum(W) (f32, by C/D row)
    f16x4 aw[8];
    f32x4 crs[8];
#pragma unroll
    for (int l = 0; l < 8; ++l) {
        float4 w = Wh[l * 64 + row * 4 + quad];
        const float s = -2.0f * K2;
        f16x2 lo = __builtin_amdgcn_cvt_pkrtz(w.x * s, w.y * s);
        f16x2 hi = __builtin_amdgcn_cvt_pkrtz(w.z * s, w.w * s);
        aw[l] = __builtin_shufflevector(lo, hi, 0, 1, 2, 3);
        float partial = w.x + w.y + w.z + w.w;
        partial += __shfl_xor(partial, 16, 64);
        partial += __shfl_xor(partial, 32, 64);   // all quads of this row agree
        f32x4 c;
#pragma unroll
        for (int i = 0; i < 4; ++i)
            c[i] = K2 * __shfl(partial, quad * 4 + i, 64);
        crs[l] = c;
    }

    // ---- Input layer: A[m=row][k] = {K2*Win.x, K2*Win.y, K2*b, 0} on quad 0
    f16x4 awin = {(__fp16)0.0f, (__fp16)0.0f, (__fp16)0.0f, (__fp16)0.0f};
    if (quad == 0) {
        float2 wr = Win[row];
        f16x2 lo = __builtin_amdgcn_cvt_pkrtz(wr.x * K2, wr.y * K2);
        f16x2 hi = __builtin_amdgcn_cvt_pkrtz(bin[row] * K2, 0.0f);
        awin = __builtin_shufflevector(lo, hi, 0, 1, 2, 3);
    }

    // ---- Output layer: A = -2*KOUT*Wout (rows 0..2), C = KOUT*rowsum(Wout)
    f16x4 awo = {(__fp16)0.0f, (__fp16)0.0f, (__fp16)0.0f, (__fp16)0.0f};
    float prt = 0.0f;
    if (row < 3) {
        float4 w = Wout[row * 4 + quad];
        const float s = -2.0f * KOUT;
        f16x2 lo = __builtin_amdgcn_cvt_pkrtz(w.x * s, w.y * s);
        f16x2 hi = __builtin_amdgcn_cvt_pkrtz(w.z * s, w.w * s);
        awo = __builtin_shufflevector(lo, hi, 0, 1, 2, 3);
        prt = w.x + w.y + w.z + w.w;
    }
    prt += __shfl_xor(prt, 16, 64);
    prt += __shfl_xor(prt, 32, 64);
    f32x4 crso;
#pragma unroll
    for (int i = 0; i < 4; ++i)
        crso[i] = KOUT * __shfl(prt, quad * 4 + i, 64);

    const f32x4 zero4 = {0.0f, 0.0f, 0.0f, 0.0f};
    const f16x2 one0  = {(__fp16)1.0f, (__fp16)0.0f};

    for (int pi = gw; pi < nPairs; pi += nWaves) {
        const int t0 = pi * 2;           // first tile of the pair
        f16x4 bf[2];
        f32x4 acco[2];

        // ---- Input layer via MFMA: B = {x, y, 1, *}; quad>0 is don't-care.
#pragma unroll
        for (int s = 0; s < 2; ++s) {
            float2 xv = x[(t0 + s) * 16 + row];
            f16x2 lo = __builtin_amdgcn_cvt_pkrtz(xv.x, xv.y);
            bf[s] = __builtin_shufflevector(lo, one0, 0, 1, 2, 3);
        }
        {
            f32x4 a0 = __builtin_amdgcn_mfma_f32_16x16x16f16(awin, bf[0], zero4, 0, 0, 0);
            f32x4 a1 = __builtin_amdgcn_mfma_f32_16x16x16f16(awin, bf[1], zero4, 0, 0, 0);
            v8pv(a0, a1, &bf[0], &bf[1]);
        }

        // ---- 8 hidden layers: 2 MFMA -> v8pv -> next B frags
#pragma unroll
        for (int l = 0; l < 8; ++l) {
            f32x4 a0 = __builtin_amdgcn_mfma_f32_16x16x16f16(aw[l], bf[0], crs[l], 0, 0, 0);
            f32x4 a1 = __builtin_amdgcn_mfma_f32_16x16x16f16(aw[l], bf[1], crs[l], 0, 0, 0);
            v8pv(a0, a1, &bf[0], &bf[1]);
        }

        // ---- Output MFMA: quad-0 lanes hold KOUT*zout in acc[0..2]
#pragma unroll
        for (int s = 0; s < 2; ++s)
            acco[s] = __builtin_amdgcn_mfma_f32_16x16x16f16(awo, bf[s], crso, 0, 0, 0);

        // ---- Sigmoid epilogue: per-value rcp (rcp is cheap)
        if (quad == 0) {
            float sa0 = __builtin_amdgcn_rcpf(__builtin_amdgcn_exp2f(acco[0][0]) + 1.0f);
            float sa1 = __builtin_amdgcn_rcpf(__builtin_amdgcn_exp2f(acco[0][1]) + 1.0f);
            float sa2 = __builtin_amdgcn_rcpf(__builtin_amdgcn_exp2f(acco[0][2]) + 1.0f);
            float sb0 = __builtin_amdgcn_rcpf(__builtin_amdgcn_exp2f(acco[1][0]) + 1.0f);
            float sb1 = __builtin_amdgcn_rcpf(__builtin_amdgcn_exp2f(acco[1][1]) + 1.0f);
            float sb2 = __builtin_amdgcn_rcpf(__builtin_amdgcn_exp2f(acco[1][2]) + 1.0f);
            const int p0 = t0 * 16 + row;
            out[p0 * 3 + 0] = sa0;
            out[p0 * 3 + 1] = sa1;
            out[p0 * 3 + 2] = sa2;
            const int p1 = p0 + 16;
            out[p1 * 3 + 0] = sb0;
            out[p1 * 3 + 1] = sb1;
            out[p1 * 3 + 2] = sb2;
        }
    }
}

extern "C" void kernel_launch(void* const* d_in, const int* in_sizes, int n_in,
                              void* d_out, int out_size, void* d_ws, size_t ws_size,
                              hipStream_t stream) {
    const float2* x    = (const float2*)d_in[0];
    const float2* Win  = (const float2*)d_in[1];
    const float*  bin  = (const float*) d_in[2];
    const float4* Wh   = (const float4*)d_in[3];
    const float4* Wout = (const float4*)d_in[4];
    float* out = (float*)d_out;

    const int n      = in_sizes[0] / 2;   // 4,194,304 points
    const int nPairs = n / 32;            // 2 tiles of 16 points per wave-iter
    const int blocks = 4096;              // 16384 waves, 8 iters/wave, no tail
    const int nWaves = blocks * 4;

    artnet_kernel<<<blocks, 256, 0, stream>>>(x, Win, bin, Wh, Wout, out, nPairs, nWaves);
}